// Round 1
// 199.636 us; speedup vs baseline: 1.0062x; 1.0062x over previous
//
#include <hip/hip_runtime.h>
#include <math.h>

// Kabsch RMSD, SINGLE fused kernel.
//
// ONE WAVE PER ROW, no LDS, no __syncthreads. 4096 waves (1024 blocks x 256
// threads). Lane l owns floats [l*12, l*12+12) of each 768-float segment =
// exactly 4 atoms. Per row, only nIter = ceil(n/256) segments are processed.
// Software-pipelined: prefetch segment it+1 while computing segment it.
// Last-segment prefetch is per-lane predicated ((it+1)*256 + lane*4 < n) so
// lanes fully past n skip their 6 float4 loads (~11% fetch savings).
// Masking uses cndmask-select (ok ? x : 0) instead of multiply-by-mask so
// never-loaded registers can't propagate NaN.
//
// After the wave-shuffle reduction of 17 f32 moments, lane 0 runs the f64
// closed-form 3x3 symmetric eigensolver (on C^T C) and writes OUT[row]
// directly -- no workspace, no second kernel. The f64 latency chain hides
// behind other waves' memory stalls.

#define NACC 17
#define ROWF 6144   // floats per row per array

__global__ __launch_bounds__(256) void kabsch_fused_kernel(
    const float* __restrict__ X,   // B x 6144 f32
    const float* __restrict__ Y,   // B x 6144 f32
    const int* __restrict__ L,     // B
    float* __restrict__ OUT,       // B
    int B)
{
    const int gwave = (int)((blockIdx.x * 256u + threadIdx.x) >> 6);
    const int lane  = threadIdx.x & 63;
    if (gwave >= B) return;
    const int row = gwave;
    const int n = L[row] + 1;              // valid atoms, 2..2047
    const int nIter = (n + 255) >> 8;      // segments of 256 atoms, 1..8
    const int myA = lane * 4;              // lane's first atom within a segment

    const float* gX = X + (size_t)row * ROWF + (size_t)lane * 12;
    const float* gY = Y + (size_t)row * ROWF + (size_t)lane * 12;

    float v[NACC];
#pragma unroll
    for (int k = 0; k < NACC; ++k) v[k] = 0.0f;

    // prologue: load segment 0 (three float4 per array, 48 B lane stride),
    // predicated so lanes past n skip (n >= 2 so lane 0 always loads).
    float4 cx0 = make_float4(0.f,0.f,0.f,0.f), cx1 = cx0, cx2 = cx0;
    float4 cy0 = cx0, cy1 = cx0, cy2 = cx0;
    if (myA < n) {
        const float4* px = (const float4*)gX;
        const float4* py = (const float4*)gY;
        cx0 = px[0]; cx1 = px[1]; cx2 = px[2];
        cy0 = py[0]; cy1 = py[1]; cy2 = py[2];
    }

    for (int it = 0; it < nIter; ++it) {
        float4 nx0 = make_float4(0.f,0.f,0.f,0.f), nx1 = nx0, nx2 = nx0;
        float4 ny0 = nx0, ny1 = nx0, ny2 = nx0;
        const bool more = (it + 1 < nIter);
        // per-lane predicated prefetch: only the final segment diverges
        if (more && ((it + 1) * 256 + myA < n)) {
            const float4* px = (const float4*)(gX + (it + 1) * 768);
            const float4* py = (const float4*)(gY + (it + 1) * 768);
            nx0 = px[0]; nx1 = px[1]; nx2 = px[2];
            ny0 = py[0]; ny1 = py[1]; ny2 = py[2];
        }

        float fx[12], fy[12];
        fx[0]=cx0.x; fx[1]=cx0.y; fx[2]=cx0.z; fx[3]=cx0.w;
        fx[4]=cx1.x; fx[5]=cx1.y; fx[6]=cx1.z; fx[7]=cx1.w;
        fx[8]=cx2.x; fx[9]=cx2.y; fx[10]=cx2.z; fx[11]=cx2.w;
        fy[0]=cy0.x; fy[1]=cy0.y; fy[2]=cy0.z; fy[3]=cy0.w;
        fy[4]=cy1.x; fy[5]=cy1.y; fy[6]=cy1.z; fy[7]=cy1.w;
        fy[8]=cy2.x; fy[9]=cy2.y; fy[10]=cy2.z; fy[11]=cy2.w;

        const int abase = it * 256 + myA;
#pragma unroll
        for (int j = 0; j < 4; ++j) {
            const bool ok = (abase + j < n);
            const float x0 = ok ? fx[3 * j + 0] : 0.0f;
            const float x1 = ok ? fx[3 * j + 1] : 0.0f;
            const float x2 = ok ? fx[3 * j + 2] : 0.0f;
            const float y0 = ok ? fy[3 * j + 0] : 0.0f;
            const float y1 = ok ? fy[3 * j + 1] : 0.0f;
            const float y2 = ok ? fy[3 * j + 2] : 0.0f;
            v[0] += x0; v[1] += x1; v[2] += x2;
            v[3] += y0; v[4] += y1; v[5] += y2;
            v[6] += x0 * x0 + x1 * x1 + x2 * x2;
            v[7] += y0 * y0 + y1 * y1 + y2 * y2;
            v[8]  += x0 * y0; v[9]  += x0 * y1; v[10] += x0 * y2;
            v[11] += x1 * y0; v[12] += x1 * y1; v[13] += x1 * y2;
            v[14] += x2 * y0; v[15] += x2 * y1; v[16] += x2 * y2;
        }

        if (more) {
            cx0 = nx0; cx1 = nx1; cx2 = nx2;
            cy0 = ny0; cy1 = ny1; cy2 = ny2;
        }
    }

    // wave-64 reduction (no LDS, no barrier)
#pragma unroll
    for (int k = 0; k < NACC; ++k) {
        float t = v[k];
        t += __shfl_down(t, 32);
        t += __shfl_down(t, 16);
        t += __shfl_down(t, 8);
        t += __shfl_down(t, 4);
        t += __shfl_down(t, 2);
        t += __shfl_down(t, 1);
        v[k] = t;
    }

    if (lane != 0) return;

    // ---- lane-0 f64 eigensolve (fused epilogue) ----
    double s[NACC];
#pragma unroll
    for (int k = 0; k < NACC; ++k) s[k] = (double)v[k];

    const double inv_n = 1.0 / (double)n;
    const double sx0 = s[0], sx1 = s[1], sx2 = s[2];
    const double sy0 = s[3], sy1 = s[4], sy2 = s[5];
    const double ssq = s[6] + s[7]
        - (sx0 * sx0 + sx1 * sx1 + sx2 * sx2) * inv_n
        - (sy0 * sy0 + sy1 * sy1 + sy2 * sy2) * inv_n;

    double C[3][3];
    C[0][0] = s[8]  - sx0 * sy0 * inv_n;
    C[0][1] = s[9]  - sx0 * sy1 * inv_n;
    C[0][2] = s[10] - sx0 * sy2 * inv_n;
    C[1][0] = s[11] - sx1 * sy0 * inv_n;
    C[1][1] = s[12] - sx1 * sy1 * inv_n;
    C[1][2] = s[13] - sx1 * sy2 * inv_n;
    C[2][0] = s[14] - sx2 * sy0 * inv_n;
    C[2][1] = s[15] - sx2 * sy1 * inv_n;
    C[2][2] = s[16] - sx2 * sy2 * inv_n;

    const double det =
          C[0][0] * (C[1][1] * C[2][2] - C[1][2] * C[2][1])
        - C[0][1] * (C[1][0] * C[2][2] - C[1][2] * C[2][0])
        + C[0][2] * (C[1][0] * C[2][1] - C[1][1] * C[2][0]);

    // A = C^T C (symmetric PSD); eigenvalues = squared singular values
    double A[3][3];
#pragma unroll
    for (int i = 0; i < 3; ++i)
#pragma unroll
        for (int j = 0; j < 3; ++j)
            A[i][j] = C[0][i] * C[0][j] + C[1][i] * C[1][j] + C[2][i] * C[2][j];

    const double q  = (A[0][0] + A[1][1] + A[2][2]) / 3.0;
    const double p1 = A[0][1] * A[0][1] + A[0][2] * A[0][2] + A[1][2] * A[1][2];
    const double a00 = A[0][0] - q, a11 = A[1][1] - q, a22 = A[2][2] - q;
    const double p2 = a00 * a00 + a11 * a11 + a22 * a22 + 2.0 * p1;
    const double p  = sqrt(p2 / 6.0);

    double e1, e2, e3;
    if (p < 1e-30) {
        e1 = e2 = e3 = q;
    } else {
        const double ip = 1.0 / p;
        const double b00 = a00 * ip, b11 = a11 * ip, b22 = a22 * ip;
        const double b01 = A[0][1] * ip, b02 = A[0][2] * ip, b12 = A[1][2] * ip;
        double r = 0.5 * (b00 * (b11 * b22 - b12 * b12)
                        - b01 * (b01 * b22 - b12 * b02)
                        + b02 * (b01 * b12 - b11 * b02));
        r = fmin(1.0, fmax(-1.0, r));
        const double phi = acos(r) / 3.0;
        e1 = q + 2.0 * p * cos(phi);
        e3 = q + 2.0 * p * cos(phi + 2.0 * M_PI / 3.0);
        e2 = 3.0 * q - e1 - e3;
    }

    const double S0 = sqrt(fmax(e1, 0.0));
    const double S1 = sqrt(fmax(e2, 0.0));
    const double S2 = sqrt(fmax(e3, 0.0));
    const double d  = (det > 0.0) ? 1.0 : ((det < 0.0) ? -1.0 : 0.0);
    const double tr = S0 + S1 + d * S2;

    const double msd = fmax(ssq - 2.0 * tr, 0.0) * inv_n;
    OUT[row] = (float)sqrt(msd + 1e-12);
}

extern "C" void kernel_launch(void* const* d_in, const int* in_sizes, int n_in,
                              void* d_out, int out_size, void* d_ws, size_t ws_size,
                              hipStream_t stream) {
    const float* X = (const float*)d_in[0];
    const float* Y = (const float*)d_in[1];
    const int* L = (const int*)d_in[2];
    float* OUT = (float*)d_out;
    (void)d_ws; (void)ws_size;

    const int B = in_sizes[2];             // 4096
    const int waves_blocks = (B * 64 + 255) / 256;   // one wave per row
    kabsch_fused_kernel<<<waves_blocks, 256, 0, stream>>>(X, Y, L, OUT, B);
}